// Round 6
// baseline (387.189 us; speedup 1.0000x reference)
//
#include <hip/hip_runtime.h>
#include <stdint.h>

#define DEV __device__ __forceinline__

typedef __attribute__((__ext_vector_type__(8))) short short8;
typedef __attribute__((__ext_vector_type__(4))) short short4_t;
typedef __attribute__((__ext_vector_type__(4))) float f32x4;
typedef __attribute__((__ext_vector_type__(4))) unsigned short ushort4_t;
typedef __attribute__((__ext_vector_type__(4))) _Float16 half4;

#define MFMA16F16(a, b, c) __builtin_amdgcn_mfma_f32_16x16x16f16((a), (b), (c), 0, 0, 0)

// ---------- helpers ----------
DEV unsigned short f2bf(float f) {
  union { float f; unsigned u; } x; x.f = f;
  unsigned u = x.u;
  unsigned r = (u + 0x7FFFu + ((u >> 16) & 1u)) >> 16;  // RNE
  return (unsigned short)r;
}

DEV unsigned short f2h(float f) {
  _Float16 h = (_Float16)f;
  unsigned short u;
  __builtin_memcpy(&u, &h, 2);
  return u;
}

DEV void gload_lds16(const void* g, void* l) {
  __builtin_amdgcn_global_load_lds(
      (const __attribute__((address_space(1))) unsigned int*)g,
      (__attribute__((address_space(3))) unsigned int*)l,
      16, 0, 0);
}

DEV short8 ld_g8(const unsigned short* p) { return *(const short8*)p; }
DEV short8 ld_s8(const unsigned short* p) { return *(const short8*)p; }

// ---------- mask dtype detection ----------
// fmt: 0 = packed bool bytes, 1 = int32 0/1, 2 = float32 0.0/1.0
__global__ void detect_mask_fmt(const unsigned int* __restrict__ mask, int* __restrict__ flag) {
  if (threadIdx.x == 0 && blockIdx.x == 0) {
    int fmt = 1;
    for (int i = 0; i < 256; ++i) {
      unsigned u = mask[i];
      if (u == 0x3F800000u) { fmt = 2; break; }
      if ((u & 0xFFFFFF00u) != 0u) { fmt = 0; break; }
    }
    *flag = fmt;
  }
}

// ---------- fused fp32 -> bf16 convert (all 7 tensors, one launch) ----------
__global__ void cvt_all(const float* __restrict__ q, const float* __restrict__ k,
                        const float* __restrict__ v,
                        const float* __restrict__ wq, const float* __restrict__ wk,
                        const float* __restrict__ wv, const float* __restrict__ wo,
                        unsigned short* __restrict__ Xq, unsigned short* __restrict__ Xk,
                        unsigned short* __restrict__ Xv, unsigned short* __restrict__ Wqb,
                        unsigned short* __restrict__ Wkb, unsigned short* __restrict__ Wvb,
                        unsigned short* __restrict__ Wob) {
  int i = blockIdx.x * 256 + threadIdx.x;
  const float* src; unsigned short* dst; int off;
  if (i < 1048576)      { src = q;  dst = Xq;  off = i; }
  else if (i < 2097152) { src = k;  dst = Xk;  off = i - 1048576; }
  else if (i < 3145728) { src = v;  dst = Xv;  off = i - 2097152; }
  else if (i < 3407872) { src = wq; dst = Wqb; off = i - 3145728; }
  else if (i < 3670016) { src = wk; dst = Wkb; off = i - 3407872; }
  else if (i < 3932160) { src = wv; dst = Wvb; off = i - 3670016; }
  else                  { src = wo; dst = Wob; off = i - 3932160; }
  float4 vv = ((const float4*)src)[off];
  ushort4_t r;
  r.x = f2bf(vv.x); r.y = f2bf(vv.y); r.z = f2bf(vv.z); r.w = f2bf(vv.w);
  ((ushort4_t*)dst)[off] = r;
}

// ---------- fused QKV projection GEMM ----------
// sel 0/1 (Q,K): bf16 out[b,h,n,d].  sel 2 (V): swapped operands -> V^T stored as
// FP16 VP_T[bh][d][n] with coalesced writes.
__global__ __launch_bounds__(256, 2) void proj_gemm(
    const unsigned short* __restrict__ Xq, const unsigned short* __restrict__ Xk,
    const unsigned short* __restrict__ Xv,
    const unsigned short* __restrict__ Wqb, const unsigned short* __restrict__ Wkb,
    const unsigned short* __restrict__ Wvb,
    const float* __restrict__ bq, const float* __restrict__ bk, const float* __restrict__ bv,
    unsigned short* __restrict__ QP, unsigned short* __restrict__ KP,
    unsigned short* __restrict__ VT) {
  const int tid = threadIdx.x;
  const int wid = tid >> 6, lane = tid & 63;
  const int l16 = lane & 15, hi = lane >> 4;
  const int m0 = blockIdx.x * 128;
  const int sel = blockIdx.y >> 3;
  const int n0 = (blockIdx.y & 7) * 128;

  const unsigned short* X; const unsigned short* W; const float* bias; unsigned short* out;
  if (sel == 0)      { X = Xq; W = Wqb; bias = bq; out = QP; }
  else if (sel == 1) { X = Xk; W = Wkb; bias = bk; out = KP; }
  else               { X = Xv; W = Wvb; bias = bv; out = VT; }

  __shared__ unsigned short stage[2 * 128 * 32];  // X tile @0, W tile @4096

  f32x4 acc[4][4] = {};
  const int wm = (wid >> 1) * 64, wn = (wid & 1) * 64;
  const int aoff = (sel == 2) ? 4096 : 0;   // V: A-frag from W tile
  const int boff = 4096 - aoff;

  for (int kt = 0; kt < 1024; kt += 32) {
#pragma unroll
    for (int t = 0; t < 4; ++t) {
      int g = wid * 4 + t;
      int c = g & 7;
      int row = c * 16 + (lane >> 2);
      int ko = (lane & 3) * 8;
      const unsigned short* src = (g < 8)
          ? (X + (size_t)(m0 + row) * 1024 + kt + ko)
          : (W + (size_t)(n0 + row) * 1024 + kt + ko);
      gload_lds16(src, (unsigned short*)((char*)stage + g * 1024));
    }
    __syncthreads();

    short8 af[4], bfr[4];
#pragma unroll
    for (int i = 0; i < 4; ++i)
      af[i] = ld_s8(&stage[aoff + (wm + i * 16 + l16) * 32 + hi * 8]);
#pragma unroll
    for (int j = 0; j < 4; ++j)
      bfr[j] = ld_s8(&stage[boff + (wn + j * 16 + l16) * 32 + hi * 8]);
#pragma unroll
    for (int i = 0; i < 4; ++i)
#pragma unroll
      for (int j = 0; j < 4; ++j)
        acc[i][j] = __builtin_amdgcn_mfma_f32_16x16x32_bf16(af[i], bfr[j], acc[i][j], 0, 0, 0);
    __syncthreads();
  }

  if (sel != 2) {
#pragma unroll
    for (int j = 0; j < 4; ++j) {
      int feat = n0 + wn + j * 16 + l16;
      float bi = bias[feat];
      int h = feat >> 6, d = feat & 63;
#pragma unroll
      for (int i = 0; i < 4; ++i) {
#pragma unroll
        for (int r = 0; r < 4; ++r) {
          int m = m0 + wm + i * 16 + hi * 4 + r;
          int b = m >> 11, n = m & 2047;
          float v = acc[i][j][r] + bi;
          out[(((size_t)(b * 16 + h)) * 2048 + n) * 64 + d] = f2bf(v);
        }
      }
    }
  } else {
    // D rows = feats, cols = tokens; store fp16 VP_T[bh][d][n]
#pragma unroll
    for (int j = 0; j < 4; ++j) {
      int tc0 = m0 + wn + j * 16;
      int b = tc0 >> 11, n = tc0 & 2047;
#pragma unroll
      for (int i = 0; i < 4; ++i) {
#pragma unroll
        for (int r = 0; r < 4; ++r) {
          int feat = n0 + wm + i * 16 + hi * 4 + r;
          int h = feat >> 6, d = feat & 63;
          float v = acc[i][j][r] + bias[feat];
          out[((size_t)(b * 16 + h) * 64 + d) * 2048 + n + l16] = f2h(v);
        }
      }
    }
  }
}

// ---------- flash attention (swapped-operand, shuffle-free softmax) ----------
// grid 1024 (XCD-swizzled), block 256 = 4 waves x 16 q-rows each, KBLK=32, 64 iters.
// S^T = mfma(K,Q): lane owns q=l16, k = 16*c0 + 4*hi + r  (register dim).
// O^T = mfma_16x16x16f16(V^T-quad, P-quad): state stays lane-local.
// W / mask / V^T staged via global_load_lds with source-side XOR swizzle.
__global__ __launch_bounds__(256, 4) void attn_kernel(
    const unsigned short* __restrict__ Q, const unsigned short* __restrict__ K,
    const unsigned short* __restrict__ VT,
    const float* __restrict__ weights,
    const unsigned char* __restrict__ mask8, const unsigned int* __restrict__ mask32,
    const int* __restrict__ mfmt,
    unsigned short* __restrict__ O) {
  const int bid = blockIdx.x;
  const int r8 = bid & 7, g = bid >> 3;
  const int qt = g & 31, bh = r8 + 8 * (g >> 5);
  const int b = bh >> 4, h = bh & 15;
  const int tid = threadIdx.x, wid = tid >> 6, lane = tid & 63;
  const int l16 = lane & 15, hi = lane >> 4;
  const size_t bh_nd = (size_t)bh * 2048 * 64;
  const size_t bh_nn = (size_t)bh * 2048 * 2048;
  const int q0 = qt * 64;
  const int qloc = wid * 16 + l16;
  const int fmt = *mfmt;
  const bool staged_mask = (fmt == 0);

  // Q fragment (B-operand: col=l16 -> q, elems d = hi*8..+7)
  short8 qf[2];
  qf[0] = ld_g8(Q + bh_nd + (size_t)(q0 + qloc) * 64 + hi * 8);
  qf[1] = ld_g8(Q + bh_nd + (size_t)(q0 + qloc) * 64 + 32 + hi * 8);

  __shared__ float wlds[2][64 * 32];            // 16 KB: [q][k] f32, swizzled
  __shared__ unsigned short vlds[2][64 * 32];   // 8 KB:  [d][k] f16, swizzled
  __shared__ unsigned char mlds[2][64 * 32];    // 4 KB:  [q][k] bytes, swizzled

  // --- per-lane staged-source offsets (with inverse swizzle baked in) ---
  // W: wave handles chunks c = wid*2, wid*2+1 (8 q-rows each, 128B rows)
  const int wr8 = lane >> 3;                       // row within chunk (= row&7)
  const int wcu = (lane & 7) ^ wr8;                // swizzled 16B-unit
  const size_t woff0 = (size_t)(q0 + wid * 16 + wr8) * 2048 + 4 * wcu;
  // V: wave handles chunk c = wid (16 d-rows, 64B rows)
  const int vr = (lane >> 2) & 15;                 // row within chunk
  const int vcu = (lane & 3) ^ (vr & 3);
  const size_t voff = (size_t)(wid * 16 + vr) * 2048 + 8 * vcu;
  // M: waves 0,1 handle chunk c = wid (32 q-rows, 32B rows)
  const int mr = lane >> 1;
  const int mcu = (lane & 1) ^ (mr & 1);
  const size_t moff = (size_t)(q0 + wid * 32 + mr) * 2048 + 16 * mcu;

  const float* wsrc = weights + bh_nn;
  const unsigned short* vsrc = VT + bh_nd;
  const unsigned char* msrc = mask8 + bh_nn;

#define STAGE(NXT, KT)                                                         \
  {                                                                            \
    gload_lds16(wsrc + woff0 + (KT), &wlds[NXT][wid * 512]);                   \
    gload_lds16(wsrc + woff0 + 8 * 2048 + (KT), &wlds[NXT][wid * 512 + 256]);  \
    gload_lds16(vsrc + voff + (KT), &vlds[NXT][wid * 512]);                    \
    if (staged_mask && wid < 2)                                                \
      gload_lds16(msrc + moff + (KT), &mlds[NXT][wid * 1024]);                 \
  }

  // accumulators: lane holds O^T[d = 16*d0 + 4*hi + r][q = l16]
  f32x4 o[4] = {};
  float mrow = -1e30f, lrow = 0.f;

  STAGE(0, 0)
  __syncthreads();

  for (int t = 0; t < 64; ++t) {
    const int cur = t & 1;
    const int kt0 = t * 32;

    // ---- K fragments FIRST (in-order vmcnt: QK wait leaves STAGE in flight)
    short8 kf00 = ld_g8(K + bh_nd + (size_t)(kt0 + l16) * 64 + hi * 8);
    short8 kf01 = ld_g8(K + bh_nd + (size_t)(kt0 + l16) * 64 + 32 + hi * 8);
    short8 kf10 = ld_g8(K + bh_nd + (size_t)(kt0 + 16 + l16) * 64 + hi * 8);
    short8 kf11 = ld_g8(K + bh_nd + (size_t)(kt0 + 16 + l16) * 64 + 32 + hi * 8);

    // ---- issue next tile's staging
    if (t < 63) STAGE(cur ^ 1, kt0 + 32)

    // ---- QK^T (swapped): S^T[k][q]
    f32x4 s0 = {}, s1 = {};
    s0 = __builtin_amdgcn_mfma_f32_16x16x32_bf16(kf00, qf[0], s0, 0, 0, 0);
    s0 = __builtin_amdgcn_mfma_f32_16x16x32_bf16(kf01, qf[1], s0, 0, 0, 0);
    s1 = __builtin_amdgcn_mfma_f32_16x16x32_bf16(kf10, qf[0], s1, 0, 0, 0);
    s1 = __builtin_amdgcn_mfma_f32_16x16x32_bf16(kf11, qf[1], s1, 0, 0, 0);

    // ---- weights (b128 from swizzled LDS) + mask -> apply
    f32x4 w0 = *(const f32x4*)&wlds[cur][qloc * 32 + 4 * ((hi + 0) ^ (l16 & 7))];
    f32x4 w1 = *(const f32x4*)&wlds[cur][qloc * 32 + 4 * ((hi + 4) ^ (l16 & 7))];
    unsigned mv0, mv1;
    if (staged_mask) {
      mv0 = *(const unsigned*)&mlds[cur][qloc * 32 + 16 * (0 ^ (l16 & 1)) + 4 * hi];
      mv1 = *(const unsigned*)&mlds[cur][qloc * 32 + 16 * (1 ^ (l16 & 1)) + 4 * hi];
    } else {
      mv0 = mv1 = 0;
      const size_t mb = bh_nn + (size_t)(q0 + qloc) * 2048 + kt0 + 4 * hi;
#pragma unroll
      for (int r = 0; r < 4; ++r) {
        mv0 |= (mask32[mb + r] ? 0xFFu : 0u) << (8 * r);
        mv1 |= (mask32[mb + 16 + r] ? 0xFFu : 0u) << (8 * r);
      }
    }
#pragma unroll
    for (int r = 0; r < 4; ++r) {
      s0[r] = ((mv0 >> (8 * r)) & 0xFF) ? -INFINITY : s0[r] * 0.125f * w0[r];
      s1[r] = ((mv1 >> (8 * r)) & 0xFF) ? -INFINITY : s1[r] * 0.125f * w1[r];
    }

    // ---- softmax: lane-local over 8, 2 shfl across hi-groups
    float tm = fmaxf(fmaxf(fmaxf(s0[0], s0[1]), fmaxf(s0[2], s0[3])),
                     fmaxf(fmaxf(s1[0], s1[1]), fmaxf(s1[2], s1[3])));
    tm = fmaxf(tm, __shfl_xor(tm, 16));
    tm = fmaxf(tm, __shfl_xor(tm, 32));
    float mnew = fmaxf(mrow, tm);
    float sc = __expf(mrow - mnew);
    mrow = mnew;
    lrow *= sc;
#pragma unroll
    for (int d0 = 0; d0 < 4; ++d0) {
      o[d0][0] *= sc; o[d0][1] *= sc; o[d0][2] *= sc; o[d0][3] *= sc;
    }
#pragma unroll
    for (int r = 0; r < 4; ++r) {
      s0[r] = __expf(s0[r] - mrow);
      s1[r] = __expf(s1[r] - mrow);
    }
    float ps = s0[0] + s0[1] + s0[2] + s0[3] + s1[0] + s1[1] + s1[2] + s1[3];
    ps += __shfl_xor(ps, 16);
    ps += __shfl_xor(ps, 32);
    lrow += ps;

    // ---- P quads (f16, lane-local) + PV (K=16 mfma, zero shuffles)
    half4 p0, p1;
    p0[0] = (_Float16)s0[0]; p0[1] = (_Float16)s0[1];
    p0[2] = (_Float16)s0[2]; p0[3] = (_Float16)s0[3];
    p1[0] = (_Float16)s1[0]; p1[1] = (_Float16)s1[1];
    p1[2] = (_Float16)s1[2]; p1[3] = (_Float16)s1[3];

#pragma unroll
    for (int d0 = 0; d0 < 4; ++d0) {
      union { short4_t s; half4 h; } v0, v1;
      v0.s = *(const short4_t*)&vlds[cur][(d0 * 16 + l16) * 32 +
              8 * ((2 * 0 + (hi >> 1)) ^ (l16 & 3)) + 4 * (hi & 1)];
      v1.s = *(const short4_t*)&vlds[cur][(d0 * 16 + l16) * 32 +
              8 * ((2 * 1 + (hi >> 1)) ^ (l16 & 3)) + 4 * (hi & 1)];
      o[d0] = MFMA16F16(v0.h, p0, o[d0]);
      o[d0] = MFMA16F16(v1.h, p1, o[d0]);
    }

    __syncthreads();
  }

  // ---- epilogue: lane-local 1/l, pack 4 consecutive d as 8B stores
  float inv = 1.0f / lrow;
  const size_t obase = (size_t)(b * 2048 + q0 + qloc) * 1024 + h * 64;
#pragma unroll
  for (int d0 = 0; d0 < 4; ++d0) {
    ushort4_t pk;
    pk.x = f2bf(o[d0][0] * inv); pk.y = f2bf(o[d0][1] * inv);
    pk.z = f2bf(o[d0][2] * inv); pk.w = f2bf(o[d0][3] * inv);
    *(ushort4_t*)&O[obase + d0 * 16 + 4 * hi] = pk;
  }
#undef STAGE
}

// ---------- output projection GEMM (fp32 out) ----------
__global__ __launch_bounds__(256, 2) void out_gemm(
    const unsigned short* __restrict__ A, const unsigned short* __restrict__ W,
    const float* __restrict__ bias, float* __restrict__ Cout) {
  const int tid = threadIdx.x;
  const int wid = tid >> 6, lane = tid & 63;
  const int l16 = lane & 15, hi = lane >> 4;
  const int m0 = blockIdx.x * 128;
  const int n0 = blockIdx.y * 128;

  __shared__ unsigned short stage[2 * 128 * 32];
  f32x4 acc[4][4] = {};
  const int wm = (wid >> 1) * 64, wn = (wid & 1) * 64;

  for (int kt = 0; kt < 1024; kt += 32) {
#pragma unroll
    for (int t = 0; t < 4; ++t) {
      int g = wid * 4 + t;
      int c = g & 7;
      int row = c * 16 + (lane >> 2);
      int ko = (lane & 3) * 8;
      const unsigned short* src = (g < 8)
          ? (A + (size_t)(m0 + row) * 1024 + kt + ko)
          : (W + (size_t)(n0 + row) * 1024 + kt + ko);
      gload_lds16(src, (unsigned short*)((char*)stage + g * 1024));
    }
    __syncthreads();

    short8 af[4], bfr[4];
#pragma unroll
    for (int i = 0; i < 4; ++i)
      af[i] = ld_s8(&stage[(wm + i * 16 + l16) * 32 + hi * 8]);
#pragma unroll
    for (int j = 0; j < 4; ++j)
      bfr[j] = ld_s8(&stage[4096 + (wn + j * 16 + l16) * 32 + hi * 8]);
#pragma unroll
    for (int i = 0; i < 4; ++i)
#pragma unroll
      for (int j = 0; j < 4; ++j)
        acc[i][j] = __builtin_amdgcn_mfma_f32_16x16x32_bf16(af[i], bfr[j], acc[i][j], 0, 0, 0);
    __syncthreads();
  }

#pragma unroll
  for (int j = 0; j < 4; ++j) {
    int feat = n0 + wn + j * 16 + l16;
    float bi = bias[feat];
#pragma unroll
    for (int i = 0; i < 4; ++i) {
#pragma unroll
      for (int r = 0; r < 4; ++r) {
        int m = m0 + wm + i * 16 + hi * 4 + r;
        Cout[(size_t)m * 1024 + feat] = acc[i][j][r] + bi;
      }
    }
  }
}

// ---------- launch ----------
extern "C" void kernel_launch(void* const* d_in, const int* in_sizes, int n_in,
                              void* d_out, int out_size, void* d_ws, size_t ws_size,
                              hipStream_t stream) {
  const float* queries = (const float*)d_in[0];
  const float* keys    = (const float*)d_in[1];
  const float* values  = (const float*)d_in[2];
  const void*  maskp   = d_in[3];
  const float* weights = (const float*)d_in[4];
  const float* Wq = (const float*)d_in[5];
  const float* bq = (const float*)d_in[6];
  const float* Wk = (const float*)d_in[7];
  const float* bk = (const float*)d_in[8];
  const float* Wv = (const float*)d_in[9];
  const float* bv = (const float*)d_in[10];
  const float* Wo = (const float*)d_in[11];
  const float* bo = (const float*)d_in[12];

  unsigned short* ws = (unsigned short*)d_ws;
  unsigned short* Xq  = ws;                 // 4194304 each; OB aliases Xq after proj
  unsigned short* Xk  = ws + 4194304;
  unsigned short* Xv  = ws + 8388608;
  unsigned short* Wqb = ws + 12582912;      // 1048576 each
  unsigned short* Wkb = ws + 13631488;
  unsigned short* Wvb = ws + 14680064;
  unsigned short* Wob = ws + 15728640;
  unsigned short* QP  = ws + 16777216;      // (b,h,n,d) bf16
  unsigned short* KP  = ws + 20971520;      // (b,h,n,d) bf16
  unsigned short* VPT = ws + 25165824;      // (b,h,d,n) fp16
  unsigned short* OB  = Xq;                 // reuse (dead after proj_gemm)
  int* mflag = (int*)(ws + 29360128);

  detect_mask_fmt<<<1, 64, 0, stream>>>((const unsigned int*)maskp, mflag);

  cvt_all<<<16384, 256, 0, stream>>>(queries, keys, values, Wq, Wk, Wv, Wo,
                                     Xq, Xk, Xv, Wqb, Wkb, Wvb, Wob);

  proj_gemm<<<dim3(32, 24), 256, 0, stream>>>(Xq, Xk, Xv, Wqb, Wkb, Wvb,
                                              bq, bk, bv, QP, KP, VPT);
  attn_kernel<<<1024, 256, 0, stream>>>(
      QP, KP, VPT, weights,
      (const unsigned char*)maskp, (const unsigned int*)maskp, mflag, OB);
  out_gemm<<<dim3(32, 8), 256, 0, stream>>>(OB, Wob, bo, (float*)d_out);
}

// Round 8
// 358.891 us; speedup vs baseline: 1.0788x; 1.0788x over previous
//
#include <hip/hip_runtime.h>
#include <stdint.h>

#define DEV __device__ __forceinline__

typedef __attribute__((__ext_vector_type__(8))) short short8;
typedef __attribute__((__ext_vector_type__(4))) float f32x4;
typedef __attribute__((__ext_vector_type__(16))) float f32x16;
typedef __attribute__((__ext_vector_type__(4))) unsigned short ushort4_t;
typedef __attribute__((__ext_vector_type__(4))) _Float16 half4;
typedef __attribute__((__ext_vector_type__(8))) _Float16 half8;

// ---------- helpers ----------
DEV unsigned short f2bf(float f) {
  union { float f; unsigned u; } x; x.f = f;
  unsigned u = x.u;
  unsigned r = (u + 0x7FFFu + ((u >> 16) & 1u)) >> 16;  // RNE
  return (unsigned short)r;
}

DEV unsigned short f2h(float f) {
  _Float16 h = (_Float16)f;
  unsigned short u;
  __builtin_memcpy(&u, &h, 2);
  return u;
}

DEV void gload_lds16(const void* g, void* l) {
  __builtin_amdgcn_global_load_lds(
      (const __attribute__((address_space(1))) unsigned int*)g,
      (__attribute__((address_space(3))) unsigned int*)l,
      16, 0, 0);
}

DEV short8 ld_g8(const unsigned short* p) { return *(const short8*)p; }
DEV short8 ld_s8(const unsigned short* p) { return *(const short8*)p; }
DEV half4 ld_h4(const unsigned short* p) {
  half4 r; __builtin_memcpy(&r, p, 8); return r;
}

// ---------- mask dtype detection ----------
// fmt: 0 = packed bool bytes, 1 = int32 0/1, 2 = float32 0.0/1.0
__global__ void detect_mask_fmt(const unsigned int* __restrict__ mask, int* __restrict__ flag) {
  if (threadIdx.x == 0 && blockIdx.x == 0) {
    int fmt = 1;
    for (int i = 0; i < 256; ++i) {
      unsigned u = mask[i];
      if (u == 0x3F800000u) { fmt = 2; break; }
      if ((u & 0xFFFFFF00u) != 0u) { fmt = 0; break; }
    }
    *flag = fmt;
  }
}

// ---------- mask -> packed bits pm[(bh*64 + t)*2048 + q], bit j = mask[q][32t+j] ----------
__global__ void pack_mask(const unsigned char* __restrict__ m8,
                          const unsigned int* __restrict__ m32,
                          const int* __restrict__ mfmt,
                          unsigned int* __restrict__ pm) {
  __shared__ unsigned int tile[32 * 65];
  const int bh = blockIdx.x >> 6;
  const int q0 = (blockIdx.x & 63) * 32;
  const int fmt = *mfmt;
  const int tid = threadIdx.x;
#pragma unroll
  for (int rnd = 0; rnd < 8; ++rnd) {
    int w = tid + rnd * 256;               // 0..2047
    int q = w >> 6, t = w & 63;
    size_t sb = ((size_t)(bh * 2048 + q0 + q)) * 2048 + t * 32;
    unsigned bits = 0;
    if (fmt == 0) {
      uint4 a = *(const uint4*)(m8 + sb);
      uint4 bq = *(const uint4*)(m8 + sb + 16);
      unsigned wa0 = a.x, wa1 = a.y, wa2 = a.z, wa3 = a.w;
      unsigned wb0 = bq.x, wb1 = bq.y, wb2 = bq.z, wb3 = bq.w;
#pragma unroll
      for (int e = 0; e < 4; ++e) {
        bits |= (((wa0 >> (8 * e)) & 0xFFu) ? 1u : 0u) << (0 + e);
        bits |= (((wa1 >> (8 * e)) & 0xFFu) ? 1u : 0u) << (4 + e);
        bits |= (((wa2 >> (8 * e)) & 0xFFu) ? 1u : 0u) << (8 + e);
        bits |= (((wa3 >> (8 * e)) & 0xFFu) ? 1u : 0u) << (12 + e);
        bits |= (((wb0 >> (8 * e)) & 0xFFu) ? 1u : 0u) << (16 + e);
        bits |= (((wb1 >> (8 * e)) & 0xFFu) ? 1u : 0u) << (20 + e);
        bits |= (((wb2 >> (8 * e)) & 0xFFu) ? 1u : 0u) << (24 + e);
        bits |= (((wb3 >> (8 * e)) & 0xFFu) ? 1u : 0u) << (28 + e);
      }
    } else {
#pragma unroll
      for (int c = 0; c < 8; ++c) {
        uint4 v = *(const uint4*)(m32 + sb + c * 4);
        bits |= (v.x ? 1u : 0u) << (c * 4);
        bits |= (v.y ? 1u : 0u) << (c * 4 + 1);
        bits |= (v.z ? 1u : 0u) << (c * 4 + 2);
        bits |= (v.w ? 1u : 0u) << (c * 4 + 3);
      }
    }
    tile[q * 65 + t] = bits;
  }
  __syncthreads();
#pragma unroll
  for (int rnd = 0; rnd < 8; ++rnd) {
    int w = tid + rnd * 256;
    int t = w >> 5, q = w & 31;
    pm[((size_t)bh * 64 + t) * 2048 + q0 + q] = tile[q * 65 + t];
  }
}

// ---------- fused fp32 -> bf16 convert (all 7 tensors, one launch) ----------
__global__ void cvt_all(const float* __restrict__ q, const float* __restrict__ k,
                        const float* __restrict__ v,
                        const float* __restrict__ wq, const float* __restrict__ wk,
                        const float* __restrict__ wv, const float* __restrict__ wo,
                        unsigned short* __restrict__ Xq, unsigned short* __restrict__ Xk,
                        unsigned short* __restrict__ Xv, unsigned short* __restrict__ Wqb,
                        unsigned short* __restrict__ Wkb, unsigned short* __restrict__ Wvb,
                        unsigned short* __restrict__ Wob) {
  int i = blockIdx.x * 256 + threadIdx.x;
  const float* src; unsigned short* dst; int off;
  if (i < 1048576)      { src = q;  dst = Xq;  off = i; }
  else if (i < 2097152) { src = k;  dst = Xk;  off = i - 1048576; }
  else if (i < 3145728) { src = v;  dst = Xv;  off = i - 2097152; }
  else if (i < 3407872) { src = wq; dst = Wqb; off = i - 3145728; }
  else if (i < 3670016) { src = wk; dst = Wkb; off = i - 3407872; }
  else if (i < 3932160) { src = wv; dst = Wvb; off = i - 3670016; }
  else                  { src = wo; dst = Wob; off = i - 3932160; }
  float4 vv = ((const float4*)src)[off];
  ushort4_t r;
  r.x = f2bf(vv.x); r.y = f2bf(vv.y); r.z = f2bf(vv.z); r.w = f2bf(vv.w);
  ((ushort4_t*)dst)[off] = r;
}

// ---------- fused QKV projection GEMM ----------
// sel 0/1 (Q,K): bf16 out[b,h,n,d].  sel 2 (V): swapped operands -> V^T stored as
// FP16 VP_T[bh][d][n] with coalesced writes.
__global__ __launch_bounds__(256, 2) void proj_gemm(
    const unsigned short* __restrict__ Xq, const unsigned short* __restrict__ Xk,
    const unsigned short* __restrict__ Xv,
    const unsigned short* __restrict__ Wqb, const unsigned short* __restrict__ Wkb,
    const unsigned short* __restrict__ Wvb,
    const float* __restrict__ bq, const float* __restrict__ bk, const float* __restrict__ bv,
    unsigned short* __restrict__ QP, unsigned short* __restrict__ KP,
    unsigned short* __restrict__ VT) {
  const int tid = threadIdx.x;
  const int wid = tid >> 6, lane = tid & 63;
  const int l16 = lane & 15, hi = lane >> 4;
  const int m0 = blockIdx.x * 128;
  const int sel = blockIdx.y >> 3;
  const int n0 = (blockIdx.y & 7) * 128;

  const unsigned short* X; const unsigned short* W; const float* bias; unsigned short* out;
  if (sel == 0)      { X = Xq; W = Wqb; bias = bq; out = QP; }
  else if (sel == 1) { X = Xk; W = Wkb; bias = bk; out = KP; }
  else               { X = Xv; W = Wvb; bias = bv; out = VT; }

  __shared__ unsigned short stage[2 * 128 * 32];  // X tile @0, W tile @4096

  f32x4 acc[4][4] = {};
  const int wm = (wid >> 1) * 64, wn = (wid & 1) * 64;
  const int aoff = (sel == 2) ? 4096 : 0;   // V: A-frag from W tile
  const int boff = 4096 - aoff;

  for (int kt = 0; kt < 1024; kt += 32) {
#pragma unroll
    for (int t = 0; t < 4; ++t) {
      int g = wid * 4 + t;
      int c = g & 7;
      int row = c * 16 + (lane >> 2);
      int ko = (lane & 3) * 8;
      const unsigned short* src = (g < 8)
          ? (X + (size_t)(m0 + row) * 1024 + kt + ko)
          : (W + (size_t)(n0 + row) * 1024 + kt + ko);
      gload_lds16(src, (unsigned short*)((char*)stage + g * 1024));
    }
    __syncthreads();

    short8 af[4], bfr[4];
#pragma unroll
    for (int i = 0; i < 4; ++i)
      af[i] = ld_s8(&stage[aoff + (wm + i * 16 + l16) * 32 + hi * 8]);
#pragma unroll
    for (int j = 0; j < 4; ++j)
      bfr[j] = ld_s8(&stage[boff + (wn + j * 16 + l16) * 32 + hi * 8]);
#pragma unroll
    for (int i = 0; i < 4; ++i)
#pragma unroll
      for (int j = 0; j < 4; ++j)
        acc[i][j] = __builtin_amdgcn_mfma_f32_16x16x32_bf16(af[i], bfr[j], acc[i][j], 0, 0, 0);
    __syncthreads();
  }

  if (sel != 2) {
#pragma unroll
    for (int j = 0; j < 4; ++j) {
      int feat = n0 + wn + j * 16 + l16;
      float bi = bias[feat];
      int h = feat >> 6, d = feat & 63;
#pragma unroll
      for (int i = 0; i < 4; ++i) {
#pragma unroll
        for (int r = 0; r < 4; ++r) {
          int m = m0 + wm + i * 16 + hi * 4 + r;
          int b = m >> 11, n = m & 2047;
          float v = acc[i][j][r] + bi;
          out[(((size_t)(b * 16 + h)) * 2048 + n) * 64 + d] = f2bf(v);
        }
      }
    }
  } else {
#pragma unroll
    for (int j = 0; j < 4; ++j) {
      int tc0 = m0 + wn + j * 16;
      int b = tc0 >> 11, n = tc0 & 2047;
#pragma unroll
      for (int i = 0; i < 4; ++i) {
#pragma unroll
        for (int r = 0; r < 4; ++r) {
          int feat = n0 + wm + i * 16 + hi * 4 + r;
          int h = feat >> 6, d = feat & 63;
          float v = acc[i][j][r] + bias[feat];
          out[((size_t)(b * 16 + h) * 64 + d) * 2048 + n + l16] = f2h(v);
        }
      }
    }
  }
}

// ---------- flash attention: 32x32 MFMA, lane-local softmax & P ----------
// grid 512: bid = qt*32 + bh  (bid%8 = bh%8 -> all q-tiles of a head on one XCD).
// block 256 = 4 waves x 32 q-rows = 128 q.  KBLK=32, 64 iters.
// S^T = mfma32(K,Q): lane q = lane&31, k = (reg&3)+8*(reg>>2)+4*(lane>>5).
// PV with permuted-k fragments: P = contiguous regs (zero shuffles, zero P-LDS).
__global__ __launch_bounds__(256, 2) void attn_kernel(
    const unsigned short* __restrict__ Q, const unsigned short* __restrict__ K,
    const unsigned short* __restrict__ VT,
    const float* __restrict__ weights,
    const unsigned int* __restrict__ pm,
    unsigned short* __restrict__ O) {
  const int bid = blockIdx.x;
  const int qt = bid >> 5, bh = bid & 31;
  const int b = bh >> 4, h = bh & 15;
  const int tid = threadIdx.x, wid = tid >> 6, lane = tid & 63;
  const int l31 = lane & 31, hh = lane >> 5;
  const size_t bh_nd = (size_t)bh * 2048 * 64;
  const int q0 = qt * 128;
  const int qg = q0 + wid * 32 + l31;      // this lane's q row

  // Q fragments: B-operand, col=q=l31, d = 16j + 8*hh + e
  short8 qf0 = ld_g8(Q + bh_nd + (size_t)qg * 64 + 0  + hh * 8);
  short8 qf1 = ld_g8(Q + bh_nd + (size_t)qg * 64 + 16 + hh * 8);
  short8 qf2 = ld_g8(Q + bh_nd + (size_t)qg * 64 + 32 + hh * 8);
  short8 qf3 = ld_g8(Q + bh_nd + (size_t)qg * 64 + 48 + hh * 8);

  __shared__ float wlds[2][128 * 32];           // 16 KB each, XOR-swizzled
  __shared__ unsigned short vlds[2][64 * 32];   // 4 KB each (f16), XOR-swizzled

  // staging geometry (linear LDS dest = base + lane*16; swizzle baked into SOURCE)
  const float* wsrc = weights + (size_t)bh * 2048 * 2048;
  const unsigned short* vsrc = VT + bh_nd;
  const int wswz = 4 * ((lane & 7) ^ (lane >> 3));                 // floats
  const int vswz = 8 * ((lane & 3) ^ ((lane >> 3) & 3));           // u16
  const int wrow_s = q0 + wid * 32 + (lane >> 3);                  // + i*8
  const int vrow_s = wid * 16 + (lane >> 2);

#define STAGE(NXT, KT)                                                        \
  {                                                                           \
    _Pragma("unroll")                                                         \
    for (int i = 0; i < 4; ++i)                                               \
      gload_lds16(wsrc + (size_t)(wrow_s + i * 8) * 2048 + (KT) + wswz,       \
                  &wlds[NXT][(wid * 4 + i) * 256]);                           \
    gload_lds16(vsrc + (size_t)vrow_s * 2048 + (KT) + vswz,                   \
                &vlds[NXT][wid * 512]);                                       \
  }

  f32x16 o0 = {}, o1 = {};
  float mrow = -1e30f, lrow = 0.f;

  STAGE(0, 0)
  __syncthreads();

  for (int t = 0; t < 64; ++t) {
    const int cur = t & 1;
    const int kt0 = t * 32;

    // ---- K fragments (A-operand: row k = l31, d = 16j + 8hh + e)
    short8 kf0 = ld_g8(K + bh_nd + (size_t)(kt0 + l31) * 64 + 0  + hh * 8);
    short8 kf1 = ld_g8(K + bh_nd + (size_t)(kt0 + l31) * 64 + 16 + hh * 8);
    short8 kf2 = ld_g8(K + bh_nd + (size_t)(kt0 + l31) * 64 + 32 + hh * 8);
    short8 kf3 = ld_g8(K + bh_nd + (size_t)(kt0 + l31) * 64 + 48 + hh * 8);
    unsigned mw = pm[((size_t)bh * 64 + t) * 2048 + qg];

    // ---- issue next tile's staging (stays in flight under compute)
    if (t < 63) STAGE(cur ^ 1, kt0 + 32)

    // ---- QK^T (S^T): 4 chained mfma over d
    f32x16 s = {};
    s = __builtin_amdgcn_mfma_f32_32x32x16_bf16(kf0, qf0, s, 0, 0, 0);
    s = __builtin_amdgcn_mfma_f32_32x32x16_bf16(kf1, qf1, s, 0, 0, 0);
    s = __builtin_amdgcn_mfma_f32_32x32x16_bf16(kf2, qf2, s, 0, 0, 0);
    s = __builtin_amdgcn_mfma_f32_32x32x16_bf16(kf3, qf3, s, 0, 0, 0);

    // ---- weights from swizzled LDS (4x b128, conflict-free phases)
    const float* wrow = &wlds[cur][(wid * 32 + l31) * 32];
    f32x4 wv[4];
    wv[0] = *(const f32x4*)&wrow[4 * ((hh + 0) ^ (l31 & 7))];
    wv[1] = *(const f32x4*)&wrow[4 * ((hh + 2) ^ (l31 & 7))];
    wv[2] = *(const f32x4*)&wrow[4 * ((hh + 4) ^ (l31 & 7))];
    wv[3] = *(const f32x4*)&wrow[4 * ((hh + 6) ^ (l31 & 7))];

    // ---- apply scale*weights + mask (branchless; reg r <-> k=(r&3)+8*(r>>2)+4hh)
    unsigned mb = mw >> (4 * hh);
#pragma unroll
    for (int r = 0; r < 16; ++r) {
      bool mk = (mb >> ((r & 3) + 8 * (r >> 2))) & 1;
      s[r] = mk ? -INFINITY : s[r] * 0.125f * wv[r >> 2][r & 3];
    }

    // ---- online softmax: lane-local 16, 1 shfl for the pair, skip-rescale
    float tm = s[0];
#pragma unroll
    for (int r = 1; r < 16; ++r) tm = fmaxf(tm, s[r]);
    float tm2 = fmaxf(tm, __shfl_xor(tm, 32));
    if (__any(tm2 > mrow)) {
      float mnew = fmaxf(mrow, tm2);
      float sc = __expf(mrow - mnew);
      lrow *= sc;
      o0 *= sc;
      o1 *= sc;
      mrow = mnew;
    }
    float ps = 0.f;
#pragma unroll
    for (int r = 0; r < 16; ++r) {
      s[r] = __expf(s[r] - mrow);
      ps += s[r];
    }
    lrow += ps;   // per-half; merged in epilogue

    // ---- P -> f16 fragments (contiguous regs; zero cross-lane)
    half8 pa0, pa1;
#pragma unroll
    for (int r = 0; r < 8; ++r) {
      pa0[r] = (_Float16)s[r];
      pa1[r] = (_Float16)s[8 + r];
    }

    // ---- PV: O^T += V'~ P~ (permuted k; V from swizzled LDS)
    {
      const unsigned short* vr = &vlds[cur][l31 * 32];
      half4 a0 = ld_h4(&vr[4 * ((hh + 0) ^ (l31 & 6))]);
      half4 a1 = ld_h4(&vr[4 * ((hh + 2) ^ (l31 & 6))]);
      half8 vf;
#pragma unroll
      for (int e = 0; e < 4; ++e) { vf[e] = a0[e]; vf[4 + e] = a1[e]; }
      o0 = __builtin_amdgcn_mfma_f32_32x32x16_f16(vf, pa0, o0, 0, 0, 0);
      half4 b0 = ld_h4(&vr[4 * ((hh + 4) ^ (l31 & 6))]);
      half4 b1 = ld_h4(&vr[4 * ((hh + 6) ^ (l31 & 6))]);
#pragma unroll
      for (int e = 0; e < 4; ++e) { vf[e] = b0[e]; vf[4 + e] = b1[e]; }
      o0 = __builtin_amdgcn_mfma_f32_32x32x16_f16(vf, pa1, o0, 0, 0, 0);
    }
    {
      const unsigned short* vr = &vlds[cur][(32 + l31) * 32];
      half4 a0 = ld_h4(&vr[4 * ((hh + 0) ^ (l31 & 6))]);
      half4 a1 = ld_h4(&vr[4 * ((hh + 2) ^ (l31 & 6))]);
      half8 vf;
#pragma unroll
      for (int e = 0; e < 4; ++e) { vf[e] = a0[e]; vf[4 + e] = a1[e]; }
      o1 = __builtin_amdgcn_mfma_f32_32x32x16_f16(vf, pa0, o1, 0, 0, 0);
      half4 b0 = ld_h4(&vr[4 * ((hh + 4) ^ (l31 & 6))]);
      half4 b1 = ld_h4(&vr[4 * ((hh + 6) ^ (l31 & 6))]);
#pragma unroll
      for (int e = 0; e < 4; ++e) { vf[e] = b0[e]; vf[4 + e] = b1[e]; }
      o1 = __builtin_amdgcn_mfma_f32_32x32x16_f16(vf, pa1, o1, 0, 0, 0);
    }

    __syncthreads();
  }

  // ---- epilogue: merge pair-sums, normalize, store bf16
  lrow += __shfl_xor(lrow, 32);
  float inv = 1.0f / lrow;
  const size_t ob = (size_t)(b * 2048 + qg) * 1024 + h * 64;
#pragma unroll
  for (int j = 0; j < 4; ++j) {
    ushort4_t pk;
    pk.x = f2bf(o0[4 * j + 0] * inv); pk.y = f2bf(o0[4 * j + 1] * inv);
    pk.z = f2bf(o0[4 * j + 2] * inv); pk.w = f2bf(o0[4 * j + 3] * inv);
    *(ushort4_t*)&O[ob + 8 * j + 4 * hh] = pk;
    ushort4_t pk1;
    pk1.x = f2bf(o1[4 * j + 0] * inv); pk1.y = f2bf(o1[4 * j + 1] * inv);
    pk1.z = f2bf(o1[4 * j + 2] * inv); pk1.w = f2bf(o1[4 * j + 3] * inv);
    *(ushort4_t*)&O[ob + 32 + 8 * j + 4 * hh] = pk1;
  }
#undef STAGE
}

// ---------- output projection GEMM (fp32 out) ----------
__global__ __launch_bounds__(256, 2) void out_gemm(
    const unsigned short* __restrict__ A, const unsigned short* __restrict__ W,
    const float* __restrict__ bias, float* __restrict__ Cout) {
  const int tid = threadIdx.x;
  const int wid = tid >> 6, lane = tid & 63;
  const int l16 = lane & 15, hi = lane >> 4;
  const int m0 = blockIdx.x * 128;
  const int n0 = blockIdx.y * 128;

  __shared__ unsigned short stage[2 * 128 * 32];
  f32x4 acc[4][4] = {};
  const int wm = (wid >> 1) * 64, wn = (wid & 1) * 64;

  for (int kt = 0; kt < 1024; kt += 32) {
#pragma unroll
    for (int t = 0; t < 4; ++t) {
      int g = wid * 4 + t;
      int c = g & 7;
      int row = c * 16 + (lane >> 2);
      int ko = (lane & 3) * 8;
      const unsigned short* src = (g < 8)
          ? (A + (size_t)(m0 + row) * 1024 + kt + ko)
          : (W + (size_t)(n0 + row) * 1024 + kt + ko);
      gload_lds16(src, (unsigned short*)((char*)stage + g * 1024));
    }
    __syncthreads();

    short8 af[4], bfr[4];
#pragma unroll
    for (int i = 0; i < 4; ++i)
      af[i] = ld_s8(&stage[(wm + i * 16 + l16) * 32 + hi * 8]);
#pragma unroll
    for (int j = 0; j < 4; ++j)
      bfr[j] = ld_s8(&stage[4096 + (wn + j * 16 + l16) * 32 + hi * 8]);
#pragma unroll
    for (int i = 0; i < 4; ++i)
#pragma unroll
      for (int j = 0; j < 4; ++j)
        acc[i][j] = __builtin_amdgcn_mfma_f32_16x16x32_bf16(af[i], bfr[j], acc[i][j], 0, 0, 0);
    __syncthreads();
  }

#pragma unroll
  for (int j = 0; j < 4; ++j) {
    int feat = n0 + wn + j * 16 + l16;
    float bi = bias[feat];
#pragma unroll
    for (int i = 0; i < 4; ++i) {
#pragma unroll
      for (int r = 0; r < 4; ++r) {
        int m = m0 + wm + i * 16 + hi * 4 + r;
        Cout[(size_t)m * 1024 + feat] = acc[i][j][r] + bi;
      }
    }
  }
}

// ---------- launch ----------
extern "C" void kernel_launch(void* const* d_in, const int* in_sizes, int n_in,
                              void* d_out, int out_size, void* d_ws, size_t ws_size,
                              hipStream_t stream) {
  const float* queries = (const float*)d_in[0];
  const float* keys    = (const float*)d_in[1];
  const float* values  = (const float*)d_in[2];
  const void*  maskp   = d_in[3];
  const float* weights = (const float*)d_in[4];
  const float* Wq = (const float*)d_in[5];
  const float* bq = (const float*)d_in[6];
  const float* Wk = (const float*)d_in[7];
  const float* bk = (const float*)d_in[8];
  const float* Wv = (const float*)d_in[9];
  const float* bv = (const float*)d_in[10];
  const float* Wo = (const float*)d_in[11];
  const float* bo = (const float*)d_in[12];

  unsigned short* ws = (unsigned short*)d_ws;
  unsigned short* Xq  = ws;                 // 4194304 u16 each
  unsigned short* Xk  = ws + 4194304;
  unsigned short* Xv  = ws + 8388608;
  unsigned short* Wqb = ws + 12582912;      // 1048576 u16 each
  unsigned short* Wkb = ws + 13631488;
  unsigned short* Wvb = ws + 14680064;
  unsigned short* Wob = ws + 15728640;
  unsigned short* QP  = ws + 16777216;      // (b,h,n,d) bf16
  unsigned short* KP  = ws + 20971520;      // (b,h,n,d) bf16
  unsigned short* VPT = ws + 25165824;      // (b,h,d,n) fp16
  unsigned short* OB  = Xq;                 // reuse (dead after proj_gemm)
  unsigned int* pmb   = (unsigned int*)(ws + 4194304);  // aliases Xk+Xv (dead after proj)
  int* mflag = (int*)(ws + 29360128);

  detect_mask_fmt<<<1, 64, 0, stream>>>((const unsigned int*)maskp, mflag);

  cvt_all<<<16384, 256, 0, stream>>>(queries, keys, values, Wq, Wk, Wv, Wo,
                                     Xq, Xk, Xv, Wqb, Wkb, Wvb, Wob);

  proj_gemm<<<dim3(32, 24), 256, 0, stream>>>(Xq, Xk, Xv, Wqb, Wkb, Wvb,
                                              bq, bk, bv, QP, KP, VPT);

  pack_mask<<<2048, 256, 0, stream>>>((const unsigned char*)maskp,
                                      (const unsigned int*)maskp, mflag, pmb);

  attn_kernel<<<512, 256, 0, stream>>>(QP, KP, VPT, weights, pmb, OB);

  out_gemm<<<dim3(32, 8), 256, 0, stream>>>(OB, Wob, bo, (float*)d_out);
}